// Round 1
// baseline (366.658 us; speedup 1.0000x reference)
//
#include <hip/hip_runtime.h>
#include <hip/hip_bf16.h>

// B=100000, C=64, R=128, H=32
// out[b,r,i,j] = sum_c w[b,r,c] * v[b,c,i]*v[b,c,j]
// w = relu(||v||_c @ W1 + b1) @ W2 + b2

#define NB 16      // batch elements per block
#define RT 8       // r rows per tile iteration

typedef float f32x4 __attribute__((ext_vector_type(4)));
typedef __bf16 bf16x8 __attribute__((ext_vector_type(8)));

static __device__ __forceinline__ unsigned short bf_bits(float f) {
  __hip_bfloat16 h = __float2bfloat16(f);
  return *reinterpret_cast<const unsigned short*>(&h);
}
static __device__ __forceinline__ unsigned int pack_bf2(float a, float b) {
  return (unsigned int)bf_bits(a) | ((unsigned int)bf_bits(b) << 16);
}

// ---- kernel 0: W2 [32][8192] fp32 -> W2T [8192][32] bf16 in workspace ----
__global__ void prep_w2t(const float* __restrict__ W2, unsigned short* __restrict__ w2t) {
  int rc = blockIdx.x * 256 + threadIdx.x;   // 0..8191
  unsigned int u[16];
#pragma unroll
  for (int kp = 0; kp < 16; ++kp) {
    float a = W2[(size_t)(2 * kp) * 8192 + rc];
    float b = W2[(size_t)(2 * kp + 1) * 8192 + rc];
    u[kp] = pack_bf2(a, b);
  }
  unsigned int* dst = reinterpret_cast<unsigned int*>(w2t + (size_t)rc * 32);
#pragma unroll
  for (int j = 0; j < 16; ++j) dst[j] = u[j];
}

// ---- main fused kernel ----
__global__ __launch_bounds__(256, 4)
void erl_main(const float* __restrict__ v, const float* __restrict__ W1,
              const float* __restrict__ b1, const float* __restrict__ b2,
              const unsigned short* __restrict__ w2t, float* __restrict__ out) {
  // LDS (padded strides chosen for 16B alignment + low bank conflict)
  __shared__ __align__(16) unsigned short W_lds[NB * 584];     // [b]: r*72 + c (r<8, c<64)
  __shared__ __align__(16) unsigned short M_lds[NB * 6 * 72];  // [(b*6+s)*72 + c]
  __shared__ __align__(16) float O_sh[NB * RT * 6];            // [b*48 + r*6 + s]
  __shared__ __align__(16) unsigned short h_lds[NB * 32];      // [b*32 + k]
  __shared__ __align__(16) float s_lds[NB * 65];               // [b*65 + c]

  const int t = threadIdx.x;
  const int b0 = blockIdx.x * NB;
  const int lane = t & 63;
  const int wid = t >> 6;
  const int x = lane >> 4;     // k-group / row-group
  const int col = lane & 15;   // M-row (stage1: rc) or N-col

  // ---------- setup: norms + outer-product entries ----------
#pragma unroll
  for (int j = 0; j < (NB * 64) / 256; ++j) {     // 4 iters
    int p = t + j * 256;
    int b = p >> 6, c = p & 63;
    const float* vp = v + ((size_t)(b0 + b) * 64 + c) * 3;
    float vx = vp[0], vy = vp[1], vz = vp[2];
    s_lds[b * 65 + c] = sqrtf(vx * vx + vy * vy + vz * vz);
    unsigned short* mp = &M_lds[b * 6 * 72 + c];
    mp[0 * 72] = bf_bits(vx * vx);
    mp[1 * 72] = bf_bits(vy * vy);
    mp[2 * 72] = bf_bits(vz * vz);
    mp[3 * 72] = bf_bits(vx * vy);
    mp[4 * 72] = bf_bits(vx * vz);
    mp[5 * 72] = bf_bits(vy * vz);
  }
  __syncthreads();

  // ---------- tiny MLP layer 1: h[b][k] ----------
#pragma unroll
  for (int j = 0; j < (NB * 32) / 256; ++j) {     // 2 iters
    int idx = t + j * 256;
    int b = idx >> 5, k = idx & 31;
    float acc = b1[k];
    for (int c = 0; c < 64; ++c)
      acc = fmaf(s_lds[b * 65 + c], W1[c * 32 + k], acc);
    h_lds[b * 32 + k] = bf_bits(fmaxf(acc, 0.f));
  }
  __syncthreads();

  // B-operand fragment for stage1: h^T [K=32][N=16b], lane: col=b, k=x*8+e
  bf16x8 hfrag = *reinterpret_cast<const bf16x8*>(&h_lds[col * 32 + x * 8]);

  for (int rt = 0; rt < 128 / RT; ++rt) {
    // ---------- stage 1: w[rc][b] = W2T[rc][k] @ h^T[k][b] + b2[rc] ----------
    // 32 rc-tiles of 16, wave handles 8; split in halves of 4 for reg pressure
#pragma unroll
    for (int half = 0; half < 2; ++half) {
      bf16x8 af[4];
      f32x4 acc1[4];
#pragma unroll
      for (int i = 0; i < 4; ++i) {
        int tile = wid * 8 + half * 4 + i;        // 0..31
        int rcg = rt * 512 + tile * 16;           // global rc base of tile
        af[i] = *reinterpret_cast<const bf16x8*>(&w2t[(size_t)(rcg + col) * 32 + x * 8]);
        acc1[i] = *reinterpret_cast<const f32x4*>(&b2[rcg + x * 4]);   // b2 -> acc init
      }
#pragma unroll
      for (int i = 0; i < 4; ++i) {
        acc1[i] = __builtin_amdgcn_mfma_f32_16x16x32_bf16(af[i], hfrag, acc1[i], 0, 0, 0);
        int rcl = (wid * 8 + half * 4 + i) * 16 + x * 4;  // local rc of acc row q=0
        int r = rcl >> 6, c = rcl & 63;
        unsigned int* wp = reinterpret_cast<unsigned int*>(&W_lds[col * 584 + r * 72 + c]);
        wp[0] = pack_bf2(acc1[i][0], acc1[i][1]);
        wp[1] = pack_bf2(acc1[i][2], acc1[i][3]);
      }
    }
    __syncthreads();

    // ---------- stage 2: O[b][r][s] = W[r][c] @ M[c][s] ----------
#pragma unroll
    for (int i = 0; i < 4; ++i) {
      int b = wid * 4 + i;
      int rr = col & 7;                 // A rows 8..15 duplicate rows 0..7 (ignored)
      int ss = (col < 6) ? col : 5;     // B cols 6..15 clamped (ignored)
      f32x4 acc2 = {0.f, 0.f, 0.f, 0.f};
#pragma unroll
      for (int ch = 0; ch < 2; ++ch) {
        bf16x8 a2 = *reinterpret_cast<const bf16x8*>(&W_lds[b * 584 + rr * 72 + ch * 32 + x * 8]);
        bf16x8 m2 = *reinterpret_cast<const bf16x8*>(&M_lds[(b * 6 + ss) * 72 + ch * 32 + x * 8]);
        acc2 = __builtin_amdgcn_mfma_f32_16x16x32_bf16(a2, m2, acc2, 0, 0, 0);
      }
      if (x < 2 && col < 6) {
#pragma unroll
        for (int q = 0; q < 4; ++q)
          O_sh[b * 48 + (x * 4 + q) * 6 + col] = acc2[q];
      }
    }
    __syncthreads();

    // ---------- flush: symmetric expand 6 -> 9, coalesced ----------
    for (int i = t; i < NB * RT * 9; i += 256) {
      int b = i / 72;
      int rem = i - b * 72;
      int r = rem / 9;
      int e = rem - r * 9;
      int ei = e / 3, ej = e - ei * 3;
      int s = (ei == ej) ? ei : (2 + ei + ej);   // xx,yy,zz,xy,xz,yz
      out[((size_t)(b0 + b) * 128 + rt * RT + r) * 9 + e] = O_sh[b * 48 + r * 6 + s];
    }
    // next stage1 writes W_lds (safe: stage2 reads done before barrier above);
    // next stage2's O_sh writes are fenced by the barrier after stage1.
  }
}

extern "C" void kernel_launch(void* const* d_in, const int* in_sizes, int n_in,
                              void* d_out, int out_size, void* d_ws, size_t ws_size,
                              hipStream_t stream) {
  const float* v  = (const float*)d_in[0];   // [100000,64,3]
  const float* W1 = (const float*)d_in[1];   // [64,32]
  const float* b1 = (const float*)d_in[2];   // [32]
  const float* W2 = (const float*)d_in[3];   // [32,8192]
  const float* b2 = (const float*)d_in[4];   // [8192]
  float* out = (float*)d_out;                // [100000,128,3,3]

  unsigned short* w2t = (unsigned short*)d_ws;  // [8192][32] bf16 = 512 KB

  prep_w2t<<<32, 256, 0, stream>>>(W2, w2t);
  erl_main<<<100000 / NB, 256, 0, stream>>>(v, W1, b1, b2, w2t, out);
}